// Round 10
// baseline (111.956 us; speedup 1.0000x reference)
//
#include <hip/hip_runtime.h>
#include <hip/hip_bf16.h>

#define NT 16384
#define CD 64

typedef __attribute__((ext_vector_type(8))) short bf16x8;
typedef __attribute__((ext_vector_type(16))) float f32x16;
typedef __attribute__((ext_vector_type(2))) int int2v;

#define AS1 __attribute__((address_space(1)))
#define AS3 __attribute__((address_space(3)))

// ---------------- projection: q = (query@Wq)*SC, k = hidden@Wk, vT = (hidden@Wv)^T ----------------
__global__ __launch_bounds__(256) void proj_kernel(
    const float* __restrict__ hidden, const float* __restrict__ query,
    const float* __restrict__ Wq, const float* __restrict__ Wk, const float* __restrict__ Wv,
    __hip_bfloat16* __restrict__ qb, __hip_bfloat16* __restrict__ kb,
    __hip_bfloat16* __restrict__ vTb)
{
    __shared__ float qin[32][64];
    __shared__ float hin[32][64];
    const int tid = threadIdx.x;
    const int R0 = blockIdx.x * 32;
    {
        int r = tid >> 3, c0 = (tid & 7) * 8;
        const float4* qs = (const float4*)(query + (size_t)(R0 + r) * CD + c0);
        const float4* hs = (const float4*)(hidden + (size_t)(R0 + r) * CD + c0);
        *(float4*)&qin[r][c0]     = qs[0];
        *(float4*)&qin[r][c0 + 4] = qs[1];
        *(float4*)&hin[r][c0]     = hs[0];
        *(float4*)&hin[r][c0 + 4] = hs[1];
    }
    __syncthreads();
    const int c = tid & 63, rg = tid >> 6;
    const float SC = 0.18033688011112042f;  // log2(e)/sqrt(64), folded into q
    float aq[8] = {0.f}, ak[8] = {0.f}, av[8] = {0.f};
    #pragma unroll 4
    for (int j = 0; j < 64; ++j) {
        float wq = Wq[j * 64 + c], wk = Wk[j * 64 + c], wv = Wv[j * 64 + c];
        #pragma unroll
        for (int r8 = 0; r8 < 8; ++r8) {
            float qv = qin[rg * 8 + r8][j];
            float hv = hin[rg * 8 + r8][j];
            aq[r8] += qv * wq;
            ak[r8] += hv * wk;
            av[r8] += hv * wv;
        }
    }
    #pragma unroll
    for (int r8 = 0; r8 < 8; ++r8) {
        int row = R0 + rg * 8 + r8;
        qb[(size_t)row * CD + c] = __float2bfloat16(aq[r8] * SC);
        kb[(size_t)row * CD + c] = __float2bfloat16(ak[r8]);
    }
    union { bf16x8 v; __hip_bfloat16 h[8]; } u;
    #pragma unroll
    for (int r8 = 0; r8 < 8; ++r8) u.h[r8] = __float2bfloat16(av[r8]);
    *(bf16x8*)(vTb + (size_t)c * NT + R0 + rg * 8) = u.v;
}

// ---------------- stage one 64-key K tile + V^T tile into LDS (2 waves, pre-swizzled source) ----------------
__device__ __forceinline__ void stage_tiles2(
    char* kdst, char* vdst,
    const __hip_bfloat16* kb, const __hip_bfloat16* vTb,
    int kv, int wid, int lane)
{
    const char* kt = (const char*)(kb + (size_t)kv * CD);
    #pragma unroll
    for (int j = 0; j < 4; ++j) {
        int ob = (wid * 4 + j) * 1024;
        int o  = ob + lane * 16;
        int so = o ^ (((o >> 7) & 7) << 4);   // XOR-swizzle baked into source
        __builtin_amdgcn_global_load_lds((const AS1 void*)(kt + so),
                                         (AS3 void*)(kdst + ob), 16, 0, 0);
    }
    #pragma unroll
    for (int j = 0; j < 4; ++j) {
        int ob = (wid * 4 + j) * 1024;
        int o  = ob + lane * 16;
        int c  = o >> 7;
        int colb = (o & 127) ^ ((c & 7) << 4);
        __builtin_amdgcn_global_load_lds(
            (const AS1 void*)((const char*)vTb + ((size_t)c * NT + kv) * 2 + colb),
            (AS3 void*)(vdst + ob), 16, 0, 0);
    }
}

// softmax (fixed-shift, base-2) for a 32-key half + pack into 2 kc-chunks of PV A-frag words.
__device__ __forceinline__ void softpack_half(
    const f32x16& s, float& lsum, int paw[2][4])
{
    float p[16];
    #pragma unroll
    for (int r = 0; r < 16; ++r) p[r] = __builtin_amdgcn_exp2f(s[r]);
    {
        float t0 = ((p[0] + p[1]) + (p[2] + p[3])) + ((p[4] + p[5]) + (p[6] + p[7]));
        float t1 = ((p[8] + p[9]) + (p[10] + p[11])) + ((p[12] + p[13]) + (p[14] + p[15]));
        lsum += t0 + t1;
    }
    int w[8];
    #pragma unroll
    for (int r2 = 0; r2 < 4; ++r2)
        #pragma unroll
        for (int u = 0; u < 2; ++u)
            asm("v_cvt_pk_bf16_f32 %0, %1, %2"
                : "=v"(w[r2 * 2 + u]) : "v"(p[4*r2 + 2*u]), "v"(p[4*r2 + 2*u + 1]));
    #pragma unroll
    for (int r2e = 0; r2e < 4; r2e += 2)
        #pragma unroll
        for (int u = 0; u < 2; ++u) {
            int2v ra = __builtin_amdgcn_permlane32_swap(w[r2e*2 + u], w[(r2e+1)*2 + u], false, false);
            paw[r2e >> 1][u]     = ra.x;
            paw[r2e >> 1][2 + u] = ra.y;
        }
}

// ---------------- flash attention: 2 waves/block, 64 q-rows/wave (2 subtiles), KV tile = 64 ----------------
// Each ds_read_b128 feeds 4 MFMAs (2 q-subtiles x 2). 2-wave blocks -> 4 independent blocks/CU
// at the 2-waves/SIMD register tier; phases decorrelate across blocks (MFMA||VALU||LDS overlap).
// Tile processed in two 32-key halves to bound register liveness (R6 structure, no spill at 84 VGPR).
__global__ __launch_bounds__(128, 2) void flash_kernel(
    const __hip_bfloat16* __restrict__ qb, const __hip_bfloat16* __restrict__ kb,
    const __hip_bfloat16* __restrict__ vTb,
    __hip_bfloat16* __restrict__ part, float* __restrict__ lbuf, float* __restrict__ out,
    int nsplit, int kvlen)
{
    __shared__ __align__(16) char kbuf[2][8192];
    __shared__ __align__(16) char vbuf[2][8192];

    const int tid  = threadIdx.x;
    const int lane = tid & 63, wid = tid >> 6;   // wid in {0,1}
    const int l31 = lane & 31, h = lane >> 5;
    const int split = blockIdx.x % nsplit;   // split%8 == XCD id -> split's K/V slice stays in one XCD L2
    const int qblk  = blockIdx.x / nsplit;
    const int q0  = qblk * 128 + wid * 64;   // wave owns q0..q0+63 (A: +0..31, B: +32..63)
    const int kv0 = split * kvlen;
    const int ntile = kvlen / 64;

    bf16x8 QfA[4], QfB[4];
    #pragma unroll
    for (int cc = 0; cc < 4; ++cc) {
        QfA[cc] = *(const bf16x8*)(qb + (size_t)(q0 + l31) * CD + cc * 16 + h * 8);
        QfB[cc] = *(const bf16x8*)(qb + (size_t)(q0 + 32 + l31) * CD + cc * 16 + h * 8);
    }

    f32x16 accA[2], accB[2];
    #pragma unroll
    for (int dt = 0; dt < 2; ++dt) {
        #pragma unroll
        for (int r = 0; r < 16; ++r) { accA[dt][r] = 0.f; accB[dt][r] = 0.f; }
    }
    float lsumA = 0.f, lsumB = 0.f;

    const int krow0 = l31, krow1 = 32 + l31;
    const int kswz  = (l31 & 7) << 4;

    stage_tiles2(kbuf[0], vbuf[0], kb, vTb, kv0, wid, lane);
    asm volatile("s_waitcnt vmcnt(0)" ::: "memory");
    __syncthreads();

    for (int t = 0; t < ntile; ++t) {
        const int b = t & 1;
        if (t + 1 < ntile)
            stage_tiles2(kbuf[b ^ 1], vbuf[b ^ 1], kb, vTb, kv0 + (t + 1) * 64, wid, lane);

        #pragma unroll
        for (int half = 0; half < 2; ++half) {
            const int krow = half ? krow1 : krow0;   // K rows = keys half*32 .. +31
            // ---- QK: each K-frag read feeds both q-subtiles ----
            f32x16 sA, sB;
            #pragma unroll
            for (int r = 0; r < 16; ++r) { sA[r] = 0.f; sB[r] = 0.f; }
            __builtin_amdgcn_s_setprio(1);
            #pragma unroll
            for (int cc = 0; cc < 4; ++cc) {
                bf16x8 k0 = *(const bf16x8*)(kbuf[b] + krow * 128 + ((cc * 32 + h * 16) ^ kswz));
                sA = __builtin_amdgcn_mfma_f32_32x32x16_bf16(k0, QfA[cc], sA, 0, 0, 0);
                sB = __builtin_amdgcn_mfma_f32_32x32x16_bf16(k0, QfB[cc], sB, 0, 0, 0);
            }
            __builtin_amdgcn_s_setprio(0);

            // ---- softmax + pack (s regs die here) ----
            int pA[2][4], pB[2][4];
            softpack_half(sA, lsumA, pA);
            softpack_half(sB, lsumB, pB);

            // ---- PV for this half's two 16-key chunks (each V-frag feeds 4 MFMAs) ----
            __builtin_amdgcn_s_setprio(1);
            #pragma unroll
            for (int j = 0; j < 2; ++j) {
                const int colb = ((half * 2 + j) * 32 + h * 16) ^ kswz;
                bf16x8 v0 = *(const bf16x8*)(vbuf[b] + krow0 * 128 + colb);
                bf16x8 v1 = *(const bf16x8*)(vbuf[b] + krow1 * 128 + colb);
                union { int i[4]; bf16x8 v; } puA, puB;
                #pragma unroll
                for (int jj = 0; jj < 4; ++jj) { puA.i[jj] = pA[j][jj]; puB.i[jj] = pB[j][jj]; }
                accA[0] = __builtin_amdgcn_mfma_f32_32x32x16_bf16(puA.v, v0, accA[0], 0, 0, 0);
                accA[1] = __builtin_amdgcn_mfma_f32_32x32x16_bf16(puA.v, v1, accA[1], 0, 0, 0);
                accB[0] = __builtin_amdgcn_mfma_f32_32x32x16_bf16(puB.v, v0, accB[0], 0, 0, 0);
                accB[1] = __builtin_amdgcn_mfma_f32_32x32x16_bf16(puB.v, v1, accB[1], 0, 0, 0);
            }
            __builtin_amdgcn_s_setprio(0);
        }

        asm volatile("s_waitcnt vmcnt(0)" ::: "memory");
        __syncthreads();
    }

    // ---- epilogue ----
    float lfA = lsumA + __shfl_xor(lsumA, 32);   // l for q0 + l31
    float lfB = lsumB + __shfl_xor(lsumB, 32);   // l for q0 + 32 + l31

    if (nsplit == 1) {
        #pragma unroll
        for (int dt = 0; dt < 2; ++dt)
            #pragma unroll
            for (int r = 0; r < 16; ++r) {
                int qrow = (r & 3) + 8 * (r >> 2) + 4 * h;
                int liA = __builtin_amdgcn_ds_bpermute(qrow * 4, __float_as_int(lfA));
                int liB = __builtin_amdgcn_ds_bpermute(qrow * 4, __float_as_int(lfB));
                out[(size_t)(q0 + qrow) * CD + dt * 32 + l31] =
                    accA[dt][r] * __builtin_amdgcn_rcpf(__int_as_float(liA));
                out[(size_t)(q0 + 32 + qrow) * CD + dt * 32 + l31] =
                    accB[dt][r] * __builtin_amdgcn_rcpf(__int_as_float(liB));
            }
    } else {
        __hip_bfloat16* pb2 = part + ((size_t)split * NT + q0) * CD;
        #pragma unroll
        for (int dt = 0; dt < 2; ++dt)
            #pragma unroll
            for (int r = 0; r < 16; ++r) {
                int qrow = (r & 3) + 8 * (r >> 2) + 4 * h;
                pb2[qrow * CD + dt * 32 + l31]        = __float2bfloat16(accA[dt][r]);
                pb2[(32 + qrow) * CD + dt * 32 + l31] = __float2bfloat16(accB[dt][r]);
            }
        if (h == 0) {
            lbuf[(size_t)split * NT + q0 + l31]      = lfA;
            lbuf[(size_t)split * NT + q0 + 32 + l31] = lfB;
        }
    }
}

// ---------------- combine the KV-splits: out = sum(part)/sum(l) ----------------
__global__ __launch_bounds__(256) void combine_kernel(
    const __hip_bfloat16* __restrict__ part, const float* __restrict__ lbuf,
    float* __restrict__ out, int S)
{
    const int tid = threadIdx.x;
    const int row = blockIdx.x * 4 + (tid >> 6);
    const int c = tid & 63;
    float L = 0.f, o = 0.f;
    for (int s = 0; s < S; ++s) {
        L += lbuf[(size_t)s * NT + row];
        o += __bfloat162float(part[((size_t)s * NT + row) * CD + c]);
    }
    out[(size_t)row * CD + c] = o / L;
}

extern "C" void kernel_launch(void* const* d_in, const int* in_sizes, int n_in,
                              void* d_out, int out_size, void* d_ws, size_t ws_size,
                              hipStream_t stream)
{
    (void)in_sizes; (void)n_in; (void)out_size;
    const float* hidden = (const float*)d_in[0];
    const float* query  = (const float*)d_in[1];
    const float* Wq = (const float*)d_in[2];
    const float* Wk = (const float*)d_in[3];
    const float* Wv = (const float*)d_in[4];
    float* out = (float*)d_out;

    char* ws = (char*)d_ws;
    __hip_bfloat16* qb  = (__hip_bfloat16*)ws;
    __hip_bfloat16* kb  = qb + (size_t)NT * CD;
    __hip_bfloat16* vTb = kb + (size_t)NT * CD;
    const size_t base = (size_t)3 * NT * CD * 2;
    const size_t per  = (size_t)NT * CD * 2 + (size_t)NT * 4;  // bf16 part + f32 l per split

    int S = 1;
    if (ws_size >= base + 16 * per) S = 16;
    else if (ws_size >= base + 8 * per) S = 8;
    else if (ws_size >= base + 4 * per) S = 4;
    else if (ws_size >= base + 2 * per) S = 2;

    __hip_bfloat16* part = (__hip_bfloat16*)(ws + base);
    float* lbuf = (float*)(ws + base + (size_t)S * NT * CD * 2);

    hipLaunchKernelGGL(proj_kernel, dim3(NT / 32), dim3(256), 0, stream,
                       hidden, query, Wq, Wk, Wv, qb, kb, vTb);
    hipLaunchKernelGGL(flash_kernel, dim3((NT / 128) * S), dim3(128), 0, stream,
                       qb, kb, vTb, part, lbuf, out, S, NT / S);
    if (S > 1)
        hipLaunchKernelGGL(combine_kernel, dim3(NT / 4), dim3(256), 0, stream,
                           part, lbuf, out, S);
}

// Round 11
// 109.432 us; speedup vs baseline: 1.0231x; 1.0231x over previous
//
#include <hip/hip_runtime.h>
#include <hip/hip_bf16.h>

#define NT 16384
#define CD 64

typedef __attribute__((ext_vector_type(8))) short bf16x8;
typedef __attribute__((ext_vector_type(16))) float f32x16;
typedef __attribute__((ext_vector_type(2))) int int2v;

#define AS1 __attribute__((address_space(1)))
#define AS3 __attribute__((address_space(3)))

// ---------------- projection: q = (query@Wq)*SC, k = hidden@Wk, vC = chunked (hidden@Wv)^T ----------------
// vC layout: per 64-key tile T: [kc(4)][feature(64)][16 keys * 2B]  (8 KB/tile, identity-staged)
__global__ __launch_bounds__(256) void proj_kernel(
    const float* __restrict__ hidden, const float* __restrict__ query,
    const float* __restrict__ Wq, const float* __restrict__ Wk, const float* __restrict__ Wv,
    __hip_bfloat16* __restrict__ qb, __hip_bfloat16* __restrict__ kb,
    __hip_bfloat16* __restrict__ vcb)
{
    __shared__ float qin[32][64];
    __shared__ float hin[32][64];
    const int tid = threadIdx.x;
    const int R0 = blockIdx.x * 32;
    {
        int r = tid >> 3, c0 = (tid & 7) * 8;
        const float4* qs = (const float4*)(query + (size_t)(R0 + r) * CD + c0);
        const float4* hs = (const float4*)(hidden + (size_t)(R0 + r) * CD + c0);
        *(float4*)&qin[r][c0]     = qs[0];
        *(float4*)&qin[r][c0 + 4] = qs[1];
        *(float4*)&hin[r][c0]     = hs[0];
        *(float4*)&hin[r][c0 + 4] = hs[1];
    }
    __syncthreads();
    const int c = tid & 63, rg = tid >> 6;
    const float SC = 0.18033688011112042f;  // log2(e)/sqrt(64), folded into q
    float aq[8] = {0.f}, ak[8] = {0.f}, av[8] = {0.f};
    #pragma unroll 4
    for (int j = 0; j < 64; ++j) {
        float wq = Wq[j * 64 + c], wk = Wk[j * 64 + c], wv = Wv[j * 64 + c];
        #pragma unroll
        for (int r8 = 0; r8 < 8; ++r8) {
            float qv = qin[rg * 8 + r8][j];
            float hv = hin[rg * 8 + r8][j];
            aq[r8] += qv * wq;
            ak[r8] += hv * wk;
            av[r8] += hv * wv;
        }
    }
    #pragma unroll
    for (int r8 = 0; r8 < 8; ++r8) {
        int row = R0 + rg * 8 + r8;
        qb[(size_t)row * CD + c] = __float2bfloat16(aq[r8] * SC);
        kb[(size_t)row * CD + c] = __float2bfloat16(ak[r8]);
    }
    union { bf16x8 v; __hip_bfloat16 h[8]; } u;
    #pragma unroll
    for (int r8 = 0; r8 < 8; ++r8) u.h[r8] = __float2bfloat16(av[r8]);
    {
        int kb0 = R0 + rg * 8;   // 8 keys, one feature c -> exactly one 16B unit of vC
        __hip_bfloat16* dst = vcb + (size_t)(kb0 >> 6) * 4096
                              + (((kb0 >> 4) & 3) * 1024) + c * 16 + ((kb0 >> 3) & 1) * 8;
        *(bf16x8*)dst = u.v;
    }
}

// ---------------- stage one 64-key tile: K -> [cc][key][32B], V -> identity copy of vC tile ----------------
__device__ __forceinline__ void stage_tiles(
    char* kdst, char* vdst,
    const __hip_bfloat16* kb, const __hip_bfloat16* vcb,
    int kv, int wid, int lane)
{
    const char* kt = (const char*)(kb + (size_t)kv * CD);
    const char* vt = (const char*)vcb + (size_t)(kv >> 6) * 8192;
    #pragma unroll
    for (int j = 0; j < 2; ++j) {
        int ob = (wid * 2 + j) * 1024;
        int o  = ob + lane * 16;
        int cc = o >> 11, key = (o >> 5) & 63, h1 = (o >> 4) & 1;
        __builtin_amdgcn_global_load_lds(
            (const AS1 void*)(kt + key * 128 + cc * 32 + h1 * 16),
            (AS3 void*)(kdst + ob), 16, 0, 0);
    }
    #pragma unroll
    for (int j = 0; j < 2; ++j) {
        int ob = (wid * 2 + j) * 1024;
        __builtin_amdgcn_global_load_lds(
            (const AS1 void*)(vt + ob + lane * 16),
            (AS3 void*)(vdst + ob), 16, 0, 0);
    }
}

// softmax (fixed-shift, base-2) for a 32-key half + pack into 2 kc-chunks of PV A-frag words.
__device__ __forceinline__ void softpack_half(
    const f32x16& s, float& lsum, int paw[2][4])
{
    float p[16];
    #pragma unroll
    for (int r = 0; r < 16; ++r) p[r] = __builtin_amdgcn_exp2f(s[r]);
    {
        float t0 = ((p[0] + p[1]) + (p[2] + p[3])) + ((p[4] + p[5]) + (p[6] + p[7]));
        float t1 = ((p[8] + p[9]) + (p[10] + p[11])) + ((p[12] + p[13]) + (p[14] + p[15]));
        lsum += t0 + t1;
    }
    int w[8];
    #pragma unroll
    for (int r2 = 0; r2 < 4; ++r2)
        #pragma unroll
        for (int u = 0; u < 2; ++u)
            asm("v_cvt_pk_bf16_f32 %0, %1, %2"
                : "=v"(w[r2 * 2 + u]) : "v"(p[4*r2 + 2*u]), "v"(p[4*r2 + 2*u + 1]));
    #pragma unroll
    for (int r2e = 0; r2e < 4; r2e += 2)
        #pragma unroll
        for (int u = 0; u < 2; ++u) {
            int2v ra = __builtin_amdgcn_permlane32_swap(w[r2e*2 + u], w[(r2e+1)*2 + u], false, false);
            paw[r2e >> 1][u]     = ra.x;
            paw[r2e >> 1][2 + u] = ra.y;
        }
}

// ---------------- flash attention: 4 waves/block, 32 q-rows/wave, KV tile = 64, LDS dbuf ----------------
// R9 schedule; chunked LDS layouts -> all ds_read_b128 fully conflict-free (64 sequential 16B units).
__global__ __launch_bounds__(256, 4) void flash_kernel(
    const __hip_bfloat16* __restrict__ qb, const __hip_bfloat16* __restrict__ kb,
    const __hip_bfloat16* __restrict__ vcb,
    __hip_bfloat16* __restrict__ part, float* __restrict__ lbuf, float* __restrict__ out,
    int nsplit, int kvlen)
{
    __shared__ __align__(16) char kbuf[2][8192];
    __shared__ __align__(16) char vbuf[2][8192];

    const int tid  = threadIdx.x;
    const int lane = tid & 63, wid = tid >> 6;
    const int l31 = lane & 31, h = lane >> 5;
    const int split = blockIdx.x % nsplit;   // split%8 == XCD id
    const int qblk  = blockIdx.x / nsplit;
    const int q0  = qblk * 128 + wid * 32;
    const int kv0 = split * kvlen;
    const int ntile = kvlen / 64;

    // Q fragment (B operand), loop-invariant
    bf16x8 Qf[4];
    #pragma unroll
    for (int cc = 0; cc < 4; ++cc)
        Qf[cc] = *(const bf16x8*)(qb + (size_t)(q0 + l31) * CD + cc * 16 + h * 8);

    f32x16 acc[2];
    #pragma unroll
    for (int dt = 0; dt < 2; ++dt)
        #pragma unroll
        for (int r = 0; r < 16; ++r) acc[dt][r] = 0.f;
    float lsum = 0.f;

    const int ro0 = l31 * 32 + h * 16;          // rows 0-31 of a chunk
    const int ro1 = (32 + l31) * 32 + h * 16;   // rows 32-63 of a chunk

    stage_tiles(kbuf[0], vbuf[0], kb, vcb, kv0, wid, lane);
    asm volatile("s_waitcnt vmcnt(0)" ::: "memory");
    __syncthreads();

    for (int t = 0; t < ntile; ++t) {
        const int b = t & 1;
        if (t + 1 < ntile)
            stage_tiles(kbuf[b ^ 1], vbuf[b ^ 1], kb, vcb, kv0 + (t + 1) * 64, wid, lane);

        // ---- S^T = K Q^T ----
        f32x16 s0, s1;
        #pragma unroll
        for (int r = 0; r < 16; ++r) { s0[r] = 0.f; s1[r] = 0.f; }
        __builtin_amdgcn_s_setprio(1);
        #pragma unroll
        for (int cc = 0; cc < 4; ++cc) {
            bf16x8 k0 = *(const bf16x8*)(kbuf[b] + cc * 2048 + ro0);
            bf16x8 k1 = *(const bf16x8*)(kbuf[b] + cc * 2048 + ro1);
            s0 = __builtin_amdgcn_mfma_f32_32x32x16_bf16(k0, Qf[cc], s0, 0, 0, 0);
            s1 = __builtin_amdgcn_mfma_f32_32x32x16_bf16(k1, Qf[cc], s1, 0, 0, 0);
        }
        __builtin_amdgcn_s_setprio(0);

        // ---- softmax + P pack (fixed shift; no max tracking) ----
        int pa[2][4], pb[2][4];
        softpack_half(s0, lsum, pa);
        softpack_half(s1, lsum, pb);

        // ---- PV ----
        __builtin_amdgcn_s_setprio(1);
        #pragma unroll
        for (int kc = 0; kc < 4; ++kc) {
            bf16x8 v0 = *(const bf16x8*)(vbuf[b] + kc * 2048 + ro0);
            bf16x8 v1 = *(const bf16x8*)(vbuf[b] + kc * 2048 + ro1);
            union { int i[4]; bf16x8 v; } pu;
            #pragma unroll
            for (int j = 0; j < 4; ++j) pu.i[j] = (kc < 2) ? pa[kc][j] : pb[kc - 2][j];
            acc[0] = __builtin_amdgcn_mfma_f32_32x32x16_bf16(pu.v, v0, acc[0], 0, 0, 0);
            acc[1] = __builtin_amdgcn_mfma_f32_32x32x16_bf16(pu.v, v1, acc[1], 0, 0, 0);
        }
        __builtin_amdgcn_s_setprio(0);

        asm volatile("s_waitcnt vmcnt(0)" ::: "memory");
        __syncthreads();
    }

    // ---- epilogue ----
    float lfull = lsum + __shfl_xor(lsum, 32);   // lanes q and q+32 both hold l[q=l31]

    if (nsplit == 1) {
        #pragma unroll
        for (int dt = 0; dt < 2; ++dt)
            #pragma unroll
            for (int r = 0; r < 16; ++r) {
                int qrow = (r & 3) + 8 * (r >> 2) + 4 * h;
                int li = __builtin_amdgcn_ds_bpermute(qrow * 4, __float_as_int(lfull));
                out[(size_t)(q0 + qrow) * CD + dt * 32 + l31] =
                    acc[dt][r] * __builtin_amdgcn_rcpf(__int_as_float(li));
            }
    } else {
        __hip_bfloat16* pb2 = part + ((size_t)split * NT + q0) * CD;
        #pragma unroll
        for (int dt = 0; dt < 2; ++dt)
            #pragma unroll
            for (int r = 0; r < 16; ++r) {
                int qrow = (r & 3) + 8 * (r >> 2) + 4 * h;
                pb2[qrow * CD + dt * 32 + l31] = __float2bfloat16(acc[dt][r]);
            }
        if (h == 0)
            lbuf[(size_t)split * NT + q0 + l31] = lfull;
    }
}

// ---------------- combine the KV-splits: out = sum(part)/sum(l) ----------------
__global__ __launch_bounds__(256) void combine_kernel(
    const __hip_bfloat16* __restrict__ part, const float* __restrict__ lbuf,
    float* __restrict__ out, int S)
{
    const int tid = threadIdx.x;
    const int row = blockIdx.x * 4 + (tid >> 6);
    const int c = tid & 63;
    float L = 0.f, o = 0.f;
    for (int s = 0; s < S; ++s) {
        L += lbuf[(size_t)s * NT + row];
        o += __bfloat162float(part[((size_t)s * NT + row) * CD + c]);
    }
    out[(size_t)row * CD + c] = o / L;
}

extern "C" void kernel_launch(void* const* d_in, const int* in_sizes, int n_in,
                              void* d_out, int out_size, void* d_ws, size_t ws_size,
                              hipStream_t stream)
{
    (void)in_sizes; (void)n_in; (void)out_size;
    const float* hidden = (const float*)d_in[0];
    const float* query  = (const float*)d_in[1];
    const float* Wq = (const float*)d_in[2];
    const float* Wk = (const float*)d_in[3];
    const float* Wv = (const float*)d_in[4];
    float* out = (float*)d_out;

    char* ws = (char*)d_ws;
    __hip_bfloat16* qb  = (__hip_bfloat16*)ws;
    __hip_bfloat16* kb  = qb + (size_t)NT * CD;
    __hip_bfloat16* vcb = kb + (size_t)NT * CD;   // chunked V, NT*CD elements
    const size_t base = (size_t)3 * NT * CD * 2;
    const size_t per  = (size_t)NT * CD * 2 + (size_t)NT * 4;  // bf16 part + f32 l per split

    int S = 1;
    if (ws_size >= base + 16 * per) S = 16;
    else if (ws_size >= base + 8 * per) S = 8;
    else if (ws_size >= base + 4 * per) S = 4;
    else if (ws_size >= base + 2 * per) S = 2;

    __hip_bfloat16* part = (__hip_bfloat16*)(ws + base);
    float* lbuf = (float*)(ws + base + (size_t)S * NT * CD * 2);

    hipLaunchKernelGGL(proj_kernel, dim3(NT / 32), dim3(256), 0, stream,
                       hidden, query, Wq, Wk, Wv, qb, kb, vcb);
    hipLaunchKernelGGL(flash_kernel, dim3((NT / 128) * S), dim3(256), 0, stream,
                       qb, kb, vcb, part, lbuf, out, S, NT / S);
    if (S > 1)
        hipLaunchKernelGGL(combine_kernel, dim3(NT / 4), dim3(256), 0, stream,
                           part, lbuf, out, S);
}